// Round 1
// baseline (1063.289 us; speedup 1.0000x reference)
//
#include <hip/hip_runtime.h>

#define K_CLS 19
#define C_CH  128
#define NPIX  65536   // 256*256
#define BATCH 8
#define BLOCKS_PER_BATCH 128   // 512 pixels per block

// ---------------------------------------------------------------------------
// Main kernel: per pixel argmax/exp + per-class weighted segment sums.
// LDS accumulators [19][129] (stride 129: bank=(cls+c)%32 -> the 19 class rows
// hit 19 distinct banks for any fixed channel c).
// ---------------------------------------------------------------------------
__global__ __launch_bounds__(256, 4)
void gcg_main(const float* __restrict__ x, const float* __restrict__ preds,
              float* __restrict__ WXg, float* __restrict__ SXg,
              float* __restrict__ deng, float* __restrict__ cntg)
{
    __shared__ float WXl[K_CLS][C_CH + 1];   // stride 129 floats
    __shared__ float SXl[K_CLS][C_CH + 1];
    __shared__ float denl[K_CLS];
    __shared__ float cntl[K_CLS];

    const int b     = blockIdx.x / BLOCKS_PER_BATCH;
    const int slice = blockIdx.x % BLOCKS_PER_BATCH;
    const int t     = threadIdx.x;

    // zero LDS accumulators
    for (int i = t; i < K_CLS * (C_CH + 1); i += 256) {
        (&WXl[0][0])[i] = 0.0f;
        (&SXl[0][0])[i] = 0.0f;
    }
    if (t < K_CLS) { denl[t] = 0.0f; cntl[t] = 0.0f; }
    __syncthreads();

    const float* xb = x     + (size_t)b * C_CH  * NPIX;
    const float* pb = preds + (size_t)b * K_CLS * NPIX;

    const int pix_per_block = NPIX / BLOCKS_PER_BATCH;   // 512
    const int n_base = slice * pix_per_block;

    for (int n0 = n_base; n0 < n_base + pix_per_block; n0 += 256) {
        const int n = n0 + t;

        // argmax over K=19 (first-max tiebreak, matches jnp.argmax)
        float best = pb[n];
        int   cls  = 0;
        #pragma unroll
        for (int k = 1; k < K_CLS; ++k) {
            float p = pb[k * NPIX + n];
            if (p > best) { best = p; cls = k; }
        }
        const float e = __expf(best);   // group-max shift cancels in the ratio

        atomicAdd(&denl[cls], e);
        atomicAdd(&cntl[cls], 1.0f);

        float* wrow = &WXl[cls][0];
        float* srow = &SXl[cls][0];
        #pragma unroll 8
        for (int c = 0; c < C_CH; ++c) {
            const float xv = xb[(size_t)c * NPIX + n];   // coalesced across lanes
            atomicAdd(&wrow[c], e * xv);
            atomicAdd(&srow[c], xv);
        }
    }
    __syncthreads();

    // flush block accumulators to global
    float* WXb = WXg + (size_t)b * K_CLS * C_CH;
    float* SXb = SXg + (size_t)b * K_CLS * C_CH;
    for (int i = t; i < K_CLS * C_CH; i += 256) {
        const int k = i / C_CH, c = i % C_CH;
        unsafeAtomicAdd(&WXb[i], WXl[k][c]);
        unsafeAtomicAdd(&SXb[i], SXl[k][c]);
    }
    if (t < K_CLS) {
        unsafeAtomicAdd(&deng[b * K_CLS + t], denl[t]);
        unsafeAtomicAdd(&cntg[b * K_CLS + t], cntl[t]);
    }
}

// ---------------------------------------------------------------------------
// Epilogue: one block per batch. ~2 MFLOP/batch of small dense algebra + softmax.
// ---------------------------------------------------------------------------
__global__ __launch_bounds__(256)
void gcg_epilogue(const float* __restrict__ WXg, const float* __restrict__ SXg,
                  const float* __restrict__ deng, const float* __restrict__ cntg,
                  const float* __restrict__ w1, const float* __restrict__ b1,
                  const float* __restrict__ w2, const float* __restrict__ b2,
                  float* __restrict__ out)
{
    __shared__ float cf [K_CLS][C_CH];      // class_feats
    __shared__ float sx [K_CLS][C_CH];      // unweighted class sums
    __shared__ float cf2[K_CLS][C_CH];      // class_feats @ w2^T
    __shared__ float S1 [C_CH][K_CLS + 1];  // per-class sums of x1
    __shared__ float gcs[C_CH][C_CH + 1];   // gc matrix (pad -> bank-safe rows)
    __shared__ float cnts[K_CLS];

    const int b = blockIdx.x;
    const int t = threadIdx.x;

    for (int i = t; i < K_CLS * C_CH; i += 256) {
        const int k = i / C_CH, c = i % C_CH;
        const float d = deng[b * K_CLS + k];
        cf[k][c] = WXg[(size_t)b * K_CLS * C_CH + i] / fmaxf(d, 1e-30f);
        sx[k][c] = SXg[(size_t)b * K_CLS * C_CH + i];
    }
    if (t < K_CLS) cnts[t] = cntg[b * K_CLS + t];
    __syncthreads();

    // cf2[k][d] = sum_c cf[k][c] * w2[d][c]
    for (int i = t; i < K_CLS * C_CH; i += 256) {
        const int k = i / C_CH, d = i % C_CH;
        float acc = 0.0f;
        for (int c = 0; c < C_CH; ++c) acc += cf[k][c] * w2[d * C_CH + c];
        cf2[k][d] = acc;
    }
    // S1[d][k] = sum_c w1[d][c] * sx[k][c] + b1[d]*cnt[k]
    for (int i = t; i < K_CLS * C_CH; i += 256) {
        const int k = i / C_CH, d = i % C_CH;
        float acc = 0.0f;
        for (int c = 0; c < C_CH; ++c) acc += w1[d * C_CH + c] * sx[k][c];
        S1[d][k] = acc + b1[d] * cnts[k];
    }
    __syncthreads();

    // gc[r][d] = (sum_k S1[r][k]*cf2[k][d] + T[r]*b2[d]) * C^-0.5
    const float s = rsqrtf((float)C_CH);
    for (int i = t; i < C_CH * C_CH; i += 256) {
        const int r = i / C_CH, d = i % C_CH;
        float T = 0.0f, acc = 0.0f;
        #pragma unroll
        for (int k = 0; k < K_CLS; ++k) {
            const float sv = S1[r][k];
            T   += sv;
            acc += sv * cf2[k][d];
        }
        gcs[r][d] = (acc + T * b2[d]) * s;
    }
    __syncthreads();

    // row softmax over d; one wave per row, lane handles cols (lane, lane+64)
    const int wave = t / 64, lane = t % 64;
    for (int r = wave; r < C_CH; r += 4) {
        float v0 = gcs[r][lane], v1 = gcs[r][lane + 64];
        float m = fmaxf(v0, v1);
        #pragma unroll
        for (int o = 32; o > 0; o >>= 1) m = fmaxf(m, __shfl_xor(m, o));
        const float e0 = __expf(v0 - m), e1 = __expf(v1 - m);
        float ssum = e0 + e1;
        #pragma unroll
        for (int o = 32; o > 0; o >>= 1) ssum += __shfl_xor(ssum, o);
        const float inv = 1.0f / ssum;
        float* orow = out + ((size_t)b * C_CH + r) * C_CH;
        orow[lane]      = e0 * inv;
        orow[lane + 64] = e1 * inv;
    }
}

extern "C" void kernel_launch(void* const* d_in, const int* in_sizes, int n_in,
                              void* d_out, int out_size, void* d_ws, size_t ws_size,
                              hipStream_t stream) {
    const float* x     = (const float*)d_in[0];
    const float* preds = (const float*)d_in[1];
    const float* w1    = (const float*)d_in[2];
    const float* b1    = (const float*)d_in[3];
    const float* w2    = (const float*)d_in[4];
    const float* b2    = (const float*)d_in[5];
    float* out = (float*)d_out;

    float* WXg  = (float*)d_ws;
    float* SXg  = WXg + BATCH * K_CLS * C_CH;
    float* deng = SXg + BATCH * K_CLS * C_CH;
    float* cntg = deng + BATCH * K_CLS;

    const size_t acc_bytes = (size_t)(2 * BATCH * K_CLS * C_CH + 2 * BATCH * K_CLS) * sizeof(float);
    hipMemsetAsync(d_ws, 0, acc_bytes, stream);

    gcg_main<<<BATCH * BLOCKS_PER_BATCH, 256, 0, stream>>>(x, preds, WXg, SXg, deng, cntg);
    gcg_epilogue<<<BATCH, 256, 0, stream>>>(WXg, SXg, deng, cntg, w1, b1, w2, b2, out);
}

// Round 3
// 483.889 us; speedup vs baseline: 2.1974x; 2.1974x over previous
//
#include <hip/hip_runtime.h>

#define K_CLS 19
#define C_CH  128
#define NPIX  65536     // 256*256
#define BATCH 8
#define BPB   128       // main-kernel blocks per batch
#define PXB   512       // pixels per block
#define TP    64        // pixels per tile
#define XSTR  65        // x_lds row stride in floats -> bank (c+n)%32, conflict-free

// ---------------------------------------------------------------------------
// Main: per-tile ballot class-sort (wave 0) + x staging (waves 1-3), then
// channel-owner register accumulation over class-contiguous runs. No atomics
// in the hot loop.
// ---------------------------------------------------------------------------
__global__ __launch_bounds__(256, 2)
void gcg_main(const float* __restrict__ x, const float* __restrict__ preds,
              float* __restrict__ WXg, float* __restrict__ SXg,
              float* __restrict__ deng, float* __restrict__ cntg)
{
    __shared__ float x_lds[C_CH * XSTR];        // 33.3 KB
    __shared__ float WXl[2][K_CLS][C_CH];       // 19.5 KB
    __shared__ float SXl[2][K_CLS][C_CH];       // 19.5 KB
    __shared__ float denl[2][K_CLS];
    __shared__ float cntl[2][K_CLS];
    __shared__ unsigned int ordc[TP];           // sorted (nn<<5)|cls
    __shared__ float es[TP];                    // e sorted

    const int t = threadIdx.x;
    const int b = blockIdx.x / BPB;
    const int slice = blockIdx.x % BPB;
    const int g = t >> 7;          // pixel-group (sorted-index half)
    const int c = t & 127;         // owned channel

    for (int i = t; i < 2 * K_CLS * C_CH; i += 256) {
        (&WXl[0][0][0])[i] = 0.0f;
        (&SXl[0][0][0])[i] = 0.0f;
    }
    if (t < 2 * K_CLS) { (&denl[0][0])[t] = 0.0f; (&cntl[0][0])[t] = 0.0f; }
    __syncthreads();

    const float* xb = x     + (size_t)b * C_CH  * NPIX;
    const float* pb = preds + (size_t)b * K_CLS * NPIX;

    for (int tile = 0; tile < PXB / TP; ++tile) {
        const int n0 = slice * PXB + tile * TP;

        if (t < 64) {
            // ---- wave 0: argmax + exp + ballot counting-sort ----
            const int n = n0 + t;
            float best = pb[n];
            int   cls  = 0;
            #pragma unroll
            for (int k = 1; k < K_CLS; ++k) {
                float p = pb[k * NPIX + n];
                if (p > best) { best = p; cls = k; }
            }
            const float e = __expf(best);
            const unsigned long long lt = (1ull << t) - 1ull;   // lane == t here
            int off = 0, pos = 0;
            #pragma unroll
            for (int k = 0; k < K_CLS; ++k) {
                unsigned long long m = __ballot(cls == k);
                if (cls == k) pos = off + (int)__popcll(m & lt);
                off += (int)__popcll(m);
            }
            ordc[pos] = (unsigned)((t << 5) | cls);
            es[pos]   = e;
        } else {
            // ---- waves 1-3: stage x tile (coalesced float4) ----
            const int tt = t - 64;
            #pragma unroll
            for (int r = 0; r < 11; ++r) {
                const int f = tt + 192 * r;
                if (f < C_CH * TP / 4) {
                    const int cc = f >> 4, nq = (f & 15) << 2;
                    const float4 v = *reinterpret_cast<const float4*>(
                        xb + (size_t)cc * NPIX + n0 + nq);
                    float* d = &x_lds[cc * XSTR + nq];
                    d[0] = v.x; d[1] = v.y; d[2] = v.z; d[3] = v.w;
                }
            }
        }
        __syncthreads();

        // ---- compute: group g scans sorted indices [g*32, g*32+32) ----
        {
            const int i0 = g * 32;
            int cur = (int)(ordc[i0] & 31u);     // uniform
            float accW = 0.f, accS = 0.f, accD = 0.f, accC = 0.f;
            for (int i = i0; i < i0 + 32; ++i) {
                const unsigned u = ordc[i];      // uniform broadcast
                const int nn = (int)(u >> 5), kk = (int)(u & 31u);
                if (kk != cur) {                 // wave-uniform branch
                    WXl[g][cur][c] += accW;
                    SXl[g][cur][c] += accS;
                    if (c == 0) { denl[g][cur] += accD; cntl[g][cur] += accC; }
                    accW = accS = accD = accC = 0.f;
                    cur = kk;
                }
                const float e  = es[i];          // uniform broadcast
                const float xv = x_lds[c * XSTR + nn];
                accW = fmaf(e, xv, accW);
                accS += xv;
                accD += e;
                accC += 1.0f;
            }
            WXl[g][cur][c] += accW;
            SXl[g][cur][c] += accS;
            if (c == 0) { denl[g][cur] += accD; cntl[g][cur] += accC; }
        }
        __syncthreads();
    }

    // ---- flush block accumulators (HW fp32 global atomic add) ----
    float* WXb = WXg + (size_t)b * K_CLS * C_CH;
    float* SXb = SXg + (size_t)b * K_CLS * C_CH;
    for (int i = t; i < K_CLS * C_CH; i += 256) {
        unsafeAtomicAdd(&WXb[i], (&WXl[0][0][0])[i] + (&WXl[1][0][0])[i]);
        unsafeAtomicAdd(&SXb[i], (&SXl[0][0][0])[i] + (&SXl[1][0][0])[i]);
    }
    if (t < K_CLS) {
        unsafeAtomicAdd(&deng[b * K_CLS + t], denl[0][t] + denl[1][t]);
        unsafeAtomicAdd(&cntg[b * K_CLS + t], cntl[0][t] + cntl[1][t]);
    }
}

// ---------------------------------------------------------------------------
// Epilogue: 16 blocks per batch; each computes cf2 (full) + an 8-row slice of
// gc + softmax. w2 staged into stride-129 LDS (conflict-free reads).
// ---------------------------------------------------------------------------
#define ROWS_PB 8

__global__ __launch_bounds__(256, 1)
void gcg_epi(const float* __restrict__ WXg, const float* __restrict__ SXg,
             const float* __restrict__ deng, const float* __restrict__ cntg,
             const float* __restrict__ w1, const float* __restrict__ b1,
             const float* __restrict__ w2, const float* __restrict__ b2,
             float* __restrict__ out)
{
    __shared__ float wbuf[C_CH * 129];          // staged w2, 66 KB
    __shared__ float cfb [K_CLS * 129];         // class feats
    __shared__ float cf2b[K_CLS * 129];         // cf @ w2^T
    __shared__ float S1  [ROWS_PB][K_CLS + 1];
    __shared__ float gcb [ROWS_PB][C_CH + 1];

    const int t = threadIdx.x;
    const int b = blockIdx.x >> 4;
    const int slice = blockIdx.x & 15;
    const int r0 = slice * ROWS_PB;

    // stage w2 rows into stride-129 LDS
    for (int f = t; f < C_CH * C_CH / 4; f += 256) {
        const int d = f >> 5, c4 = (f & 31) << 2;
        const float4 v = *reinterpret_cast<const float4*>(w2 + d * C_CH + c4);
        float* p = &wbuf[d * 129 + c4];
        p[0] = v.x; p[1] = v.y; p[2] = v.z; p[3] = v.w;
    }
    // cf = WX / den
    for (int i = t; i < K_CLS * C_CH; i += 256) {
        const int k = i >> 7, cc = i & 127;
        const float den = deng[b * K_CLS + k];
        cfb[k * 129 + cc] = WXg[(size_t)b * K_CLS * C_CH + i] / fmaxf(den, 1e-30f);
    }
    __syncthreads();

    // cf2[k][d] = sum_c cf[k][c] * w2[d][c]   (cf broadcast, wbuf conflict-free)
    for (int i = t; i < K_CLS * C_CH; i += 256) {
        const int k = i >> 7, d = i & 127;
        float acc = 0.f;
        #pragma unroll 4
        for (int cc = 0; cc < C_CH; ++cc) acc += cfb[k * 129 + cc] * wbuf[d * 129 + cc];
        cf2b[k * 129 + d] = acc;
    }
    // S1 slice: rows r0..r0+7
    if (t < ROWS_PB * K_CLS) {
        const int rr = t / K_CLS, kk = t % K_CLS;
        const float* w1r = w1 + (size_t)(r0 + rr) * C_CH;
        const float* sxr = SXg + (size_t)b * K_CLS * C_CH + kk * C_CH;
        float acc = 0.f;
        for (int cc = 0; cc < C_CH; ++cc) acc += w1r[cc] * sxr[cc];
        S1[rr][kk] = acc + b1[r0 + rr] * cntg[b * K_CLS + kk];
    }
    __syncthreads();

    const float s = rsqrtf((float)C_CH);
    for (int o = t; o < ROWS_PB * C_CH; o += 256) {
        const int rr = o >> 7, d = o & 127;
        float T = 0.f, acc = 0.f;
        #pragma unroll
        for (int k = 0; k < K_CLS; ++k) {
            const float sv = S1[rr][k];
            T += sv;
            acc = fmaf(sv, cf2b[k * 129 + d], acc);
        }
        gcb[rr][d] = (acc + T * b2[d]) * s;
    }
    __syncthreads();

    // row softmax: wave wv handles rows wv, wv+4
    const int wv = t >> 6, lane = t & 63;
    for (int rr = wv; rr < ROWS_PB; rr += 4) {
        float v0 = gcb[rr][lane], v1 = gcb[rr][lane + 64];
        float m = fmaxf(v0, v1);
        #pragma unroll
        for (int o2 = 32; o2 > 0; o2 >>= 1) m = fmaxf(m, __shfl_xor(m, o2));
        const float e0 = __expf(v0 - m), e1 = __expf(v1 - m);
        float ssum = e0 + e1;
        #pragma unroll
        for (int o2 = 32; o2 > 0; o2 >>= 1) ssum += __shfl_xor(ssum, o2);
        const float inv = 1.0f / ssum;
        float* orow = out + ((size_t)b * C_CH + r0 + rr) * C_CH;
        orow[lane]      = e0 * inv;
        orow[lane + 64] = e1 * inv;
    }
}

extern "C" void kernel_launch(void* const* d_in, const int* in_sizes, int n_in,
                              void* d_out, int out_size, void* d_ws, size_t ws_size,
                              hipStream_t stream) {
    const float* x     = (const float*)d_in[0];
    const float* preds = (const float*)d_in[1];
    const float* w1    = (const float*)d_in[2];
    const float* b1    = (const float*)d_in[3];
    const float* w2    = (const float*)d_in[4];
    const float* b2    = (const float*)d_in[5];
    float* out = (float*)d_out;

    float* WXg  = (float*)d_ws;
    float* SXg  = WXg + BATCH * K_CLS * C_CH;
    float* deng = SXg + BATCH * K_CLS * C_CH;
    float* cntg = deng + BATCH * K_CLS;

    const size_t acc_bytes =
        (size_t)(2 * BATCH * K_CLS * C_CH + 2 * BATCH * K_CLS) * sizeof(float);
    hipMemsetAsync(d_ws, 0, acc_bytes, stream);

    gcg_main<<<BATCH * BPB, 256, 0, stream>>>(x, preds, WXg, SXg, deng, cntg);
    gcg_epi<<<BATCH * 16, 256, 0, stream>>>(WXg, SXg, deng, cntg, w1, b1, w2, b2, out);
}

// Round 5
// 445.250 us; speedup vs baseline: 2.3881x; 1.0868x over previous
//
#include <hip/hip_runtime.h>

#define K_CLS 19
#define C_CH  128
#define NPIX  65536     // 256*256
#define BATCH 8
#define ROWSTRIDE 39    // per-thread acc row: 19 WX + 19 SX + 1 pad

// ws layout (f32 units):
//   WXg  @ 0       (19456)
//   SXg  @ 19456   (19456)
//   deng @ 38912   (152)
//   cntg @ 39064   (152)
//   META @ 39216   (524288 u32: e-bits | cls)   -> ends 563504
//   CF2  @ 563504  (19456)
//   S1   @ 582960  (19456)
//   END  @ 602416 f32 = 2.30 MB

// ---------------------------------------------------------------------------
// Pass 1: per-pixel argmax + exp over preds; write packed meta u32
// (e mantissa-truncated to 18 bits, low 5 bits = cls); reduce den/cnt.
// ---------------------------------------------------------------------------
__global__ __launch_bounds__(256, 2)
void gcg_pass1(const float* __restrict__ preds, unsigned* __restrict__ meta,
               float* __restrict__ deng, float* __restrict__ cntg)
{
    __shared__ float denl[K_CLS], cntl[K_CLS];
    const int t = threadIdx.x;
    const int b = blockIdx.x >> 6, blk = blockIdx.x & 63;
    if (t < K_CLS) { denl[t] = 0.f; cntl[t] = 0.f; }
    __syncthreads();

    const int n0 = blk * 1024 + 4 * t;
    const float* pb = preds + (size_t)b * K_CLS * NPIX + n0;

    float4 bv = *reinterpret_cast<const float4*>(pb);
    int k0 = 0, k1 = 0, k2 = 0, k3 = 0;
    #pragma unroll
    for (int k = 1; k < K_CLS; ++k) {
        const float4 p = *reinterpret_cast<const float4*>(pb + (size_t)k * NPIX);
        if (p.x > bv.x) { bv.x = p.x; k0 = k; }
        if (p.y > bv.y) { bv.y = p.y; k1 = k; }
        if (p.z > bv.z) { bv.z = p.z; k2 = k; }
        if (p.w > bv.w) { bv.w = p.w; k3 = k; }
    }
    uint4 m;
    m.x = (__float_as_uint(__expf(bv.x)) & 0xFFFFFFE0u) | (unsigned)k0;
    m.y = (__float_as_uint(__expf(bv.y)) & 0xFFFFFFE0u) | (unsigned)k1;
    m.z = (__float_as_uint(__expf(bv.z)) & 0xFFFFFFE0u) | (unsigned)k2;
    m.w = (__float_as_uint(__expf(bv.w)) & 0xFFFFFFE0u) | (unsigned)k3;
    *reinterpret_cast<uint4*>(meta + (size_t)b * NPIX + n0) = m;

    atomicAdd(&denl[k0], __uint_as_float(m.x & 0xFFFFFFE0u)); atomicAdd(&cntl[k0], 1.f);
    atomicAdd(&denl[k1], __uint_as_float(m.y & 0xFFFFFFE0u)); atomicAdd(&cntl[k1], 1.f);
    atomicAdd(&denl[k2], __uint_as_float(m.z & 0xFFFFFFE0u)); atomicAdd(&cntl[k2], 1.f);
    atomicAdd(&denl[k3], __uint_as_float(m.w & 0xFFFFFFE0u)); atomicAdd(&cntl[k3], 1.f);
    __syncthreads();
    if (t < K_CLS) {
        unsafeAtomicAdd(&deng[b * K_CLS + t], denl[t]);
        unsafeAtomicAdd(&cntg[b * K_CLS + t], cntl[t]);
    }
}

// ---------------------------------------------------------------------------
// Pass 2: wave = one channel, lanes = pixels (coalesced 1KB x-loads).
// Per-thread private LDS accumulator row -> no atomics, no hot-loop barriers.
// ---------------------------------------------------------------------------
__global__ __launch_bounds__(256, 4)
void gcg_pass2(const float* __restrict__ x, const unsigned* __restrict__ meta,
               float* __restrict__ WXg, float* __restrict__ SXg)
{
    __shared__ float acc[256 * ROWSTRIDE];   // 39936 B -> 4 blocks/CU
    const int t = threadIdx.x, w = t >> 6, l = t & 63;
    const int b = blockIdx.x >> 7;           // 1024 blocks = 8 b * 32 cgrp * 4 q
    const int r = blockIdx.x & 127;
    const int cgrp = r >> 2, q = r & 3;
    const int c = cgrp * 4 + w;

    float* arow = &acc[t * ROWSTRIDE];
    #pragma unroll
    for (int s = 0; s < ROWSTRIDE; ++s) arow[s] = 0.f;

    const float*    xr = x    + ((size_t)(b * C_CH + c)) * NPIX + q * 16384;
    const unsigned* mr = meta + (size_t)b * NPIX + q * 16384;

    #pragma unroll 4
    for (int i = 0; i < 64; ++i) {
        const int px = i * 256 + 4 * l;
        const float4 x4 = *reinterpret_cast<const float4*>(xr + px);
        const uint4  m4 = *reinterpret_cast<const uint4*>(mr + px);
        {   const int k = (int)(m4.x & 31u);
            const float e = __uint_as_float(m4.x & 0xFFFFFFE0u);
            const float vW = arow[k], vS = arow[19 + k];
            arow[k] = fmaf(e, x4.x, vW); arow[19 + k] = vS + x4.x;
        }
        {   const int k = (int)(m4.y & 31u);
            const float e = __uint_as_float(m4.y & 0xFFFFFFE0u);
            const float vW = arow[k], vS = arow[19 + k];
            arow[k] = fmaf(e, x4.y, vW); arow[19 + k] = vS + x4.y;
        }
        {   const int k = (int)(m4.z & 31u);
            const float e = __uint_as_float(m4.z & 0xFFFFFFE0u);
            const float vW = arow[k], vS = arow[19 + k];
            arow[k] = fmaf(e, x4.z, vW); arow[19 + k] = vS + x4.z;
        }
        {   const int k = (int)(m4.w & 31u);
            const float e = __uint_as_float(m4.w & 0xFFFFFFE0u);
            const float vW = arow[k], vS = arow[19 + k];
            arow[k] = fmaf(e, x4.w, vW); arow[19 + k] = vS + x4.w;
        }
    }
    __syncthreads();

    // flush: 152 jobs = {WX,SX} x 4 waves x 19 classes; each sums 64 lane-rows
    if (t < 2 * 4 * K_CLS) {
        const int arr = t / (4 * K_CLS), rem = t % (4 * K_CLS);
        const int ww = rem / K_CLS, k = rem % K_CLS;
        const int slot = arr * K_CLS + k;
        float s0 = 0.f;
        #pragma unroll 8
        for (int ll = 0; ll < 64; ++ll)
            s0 += acc[(ww * 64 + ll) * ROWSTRIDE + slot];
        const int cc = cgrp * 4 + ww;
        float* dst = (arr == 0) ? WXg : SXg;
        unsafeAtomicAdd(&dst[((size_t)b * K_CLS + k) * C_CH + cc], s0);
    }
}

// ---------------------------------------------------------------------------
// Epilogue A: per batch (8 blocks): cf2[k][d] = (WX/den) @ w2^T,
// S1[d][k] = w1 @ SX^T + b1*cnt. Weights staged in LDS (stride 129).
// ---------------------------------------------------------------------------
__global__ __launch_bounds__(256, 1)
void gcg_epiA(const float* __restrict__ WXg, const float* __restrict__ SXg,
              const float* __restrict__ deng, const float* __restrict__ cntg,
              const float* __restrict__ w1, const float* __restrict__ b1,
              const float* __restrict__ w2,
              float* __restrict__ cf2g, float* __restrict__ S1g)
{
    __shared__ float wb[C_CH * 129];
    __shared__ float fb[K_CLS * 129];
    const int t = threadIdx.x, b = blockIdx.x;

    for (int f = t; f < C_CH * C_CH / 4; f += 256) {
        const int d = f >> 5, c4 = (f & 31) << 2;
        const float4 v = *reinterpret_cast<const float4*>(w2 + d * C_CH + c4);
        float* p = &wb[d * 129 + c4];
        p[0] = v.x; p[1] = v.y; p[2] = v.z; p[3] = v.w;
    }
    for (int i = t; i < K_CLS * C_CH; i += 256) {
        const int k = i >> 7, c = i & 127;
        fb[k * 129 + c] = WXg[(size_t)b * K_CLS * C_CH + i] /
                          fmaxf(deng[b * K_CLS + k], 1e-30f);
    }
    __syncthreads();
    for (int i = t; i < K_CLS * C_CH; i += 256) {
        const int k = i >> 7, d = i & 127;
        float a = 0.f;
        #pragma unroll 8
        for (int c = 0; c < C_CH; ++c) a = fmaf(fb[k * 129 + c], wb[d * 129 + c], a);
        cf2g[(size_t)b * K_CLS * C_CH + k * C_CH + d] = a;
    }
    __syncthreads();
    for (int f = t; f < C_CH * C_CH / 4; f += 256) {
        const int d = f >> 5, c4 = (f & 31) << 2;
        const float4 v = *reinterpret_cast<const float4*>(w1 + d * C_CH + c4);
        float* p = &wb[d * 129 + c4];
        p[0] = v.x; p[1] = v.y; p[2] = v.z; p[3] = v.w;
    }
    for (int i = t; i < K_CLS * C_CH; i += 256)
        fb[(i >> 7) * 129 + (i & 127)] = SXg[(size_t)b * K_CLS * C_CH + i];
    __syncthreads();
    for (int i = t; i < K_CLS * C_CH; i += 256) {
        const int d = i / K_CLS, k = i % K_CLS;
        float a = 0.f;
        #pragma unroll 8
        for (int c = 0; c < C_CH; ++c) a = fmaf(wb[d * 129 + c], fb[k * 129 + c], a);
        S1g[(size_t)b * C_CH * K_CLS + d * K_CLS + k] = a + b1[d] * cntg[b * K_CLS + k];
    }
}

// ---------------------------------------------------------------------------
// Epilogue B: 8 blocks/batch, 16 gc rows each: gc = S1 @ cf2 + T*b2, row softmax.
// ---------------------------------------------------------------------------
__global__ __launch_bounds__(256, 1)
void gcg_epiB(const float* __restrict__ cf2g, const float* __restrict__ S1g,
              const float* __restrict__ b2, float* __restrict__ out)
{
    __shared__ float cf2b[K_CLS * 132];
    __shared__ float S1b[16][20];
    __shared__ float b2b[C_CH];
    __shared__ float gcb[16][C_CH + 1];
    const int t = threadIdx.x;
    const int b = blockIdx.x >> 3, sl = blockIdx.x & 7;
    const int r0 = sl * 16;

    for (int i = t; i < K_CLS * C_CH; i += 256)
        cf2b[(i >> 7) * 132 + (i & 127)] = cf2g[(size_t)b * K_CLS * C_CH + i];
    for (int i = t; i < 16 * K_CLS; i += 256) {      // FIX: 304 jobs > 256 threads
        const int rr = i / K_CLS, k = i % K_CLS;
        S1b[rr][k] = S1g[(size_t)b * C_CH * K_CLS + (r0 + rr) * K_CLS + k];
    }
    if (t < C_CH) b2b[t] = b2[t];
    __syncthreads();

    {
        const int rr = t >> 4, d0 = (t & 15) * 8;
        float a0=0,a1=0,a2=0,a3=0,a4=0,a5=0,a6=0,a7=0, T = 0.f;
        #pragma unroll
        for (int k = 0; k < K_CLS; ++k) {
            const float sv = S1b[rr][k];
            T += sv;
            const float* row = &cf2b[k * 132 + d0];
            a0 = fmaf(sv, row[0], a0); a1 = fmaf(sv, row[1], a1);
            a2 = fmaf(sv, row[2], a2); a3 = fmaf(sv, row[3], a3);
            a4 = fmaf(sv, row[4], a4); a5 = fmaf(sv, row[5], a5);
            a6 = fmaf(sv, row[6], a6); a7 = fmaf(sv, row[7], a7);
        }
        const float s = 0.08838834764831845f;   // 128^-0.5
        float* g = &gcb[rr][d0];
        g[0]=(a0+T*b2b[d0+0])*s; g[1]=(a1+T*b2b[d0+1])*s;
        g[2]=(a2+T*b2b[d0+2])*s; g[3]=(a3+T*b2b[d0+3])*s;
        g[4]=(a4+T*b2b[d0+4])*s; g[5]=(a5+T*b2b[d0+5])*s;
        g[6]=(a6+T*b2b[d0+6])*s; g[7]=(a7+T*b2b[d0+7])*s;
    }
    __syncthreads();

    const int wv = t >> 6, lane = t & 63;
    for (int rr = wv; rr < 16; rr += 4) {
        float v0 = gcb[rr][lane], v1 = gcb[rr][lane + 64];
        float m = fmaxf(v0, v1);
        #pragma unroll
        for (int o = 32; o > 0; o >>= 1) m = fmaxf(m, __shfl_xor(m, o));
        const float e0 = __expf(v0 - m), e1 = __expf(v1 - m);
        float ss = e0 + e1;
        #pragma unroll
        for (int o = 32; o > 0; o >>= 1) ss += __shfl_xor(ss, o);
        const float inv = 1.0f / ss;
        float* orow = out + ((size_t)b * C_CH + r0 + rr) * C_CH;
        orow[lane]      = e0 * inv;
        orow[lane + 64] = e1 * inv;
    }
}

extern "C" void kernel_launch(void* const* d_in, const int* in_sizes, int n_in,
                              void* d_out, int out_size, void* d_ws, size_t ws_size,
                              hipStream_t stream) {
    const float* x     = (const float*)d_in[0];
    const float* preds = (const float*)d_in[1];
    const float* w1    = (const float*)d_in[2];
    const float* b1    = (const float*)d_in[3];
    const float* w2    = (const float*)d_in[4];
    const float* b2    = (const float*)d_in[5];
    float* out = (float*)d_out;

    float* ws   = (float*)d_ws;
    float* WXg  = ws;
    float* SXg  = ws + 19456;
    float* deng = ws + 38912;
    float* cntg = ws + 39064;
    unsigned* META = (unsigned*)(ws + 39216);
    float* CF2  = ws + 563504;
    float* S1   = ws + 582960;

    hipMemsetAsync(d_ws, 0, 39216 * sizeof(float), stream);

    gcg_pass1<<<BATCH * 64, 256, 0, stream>>>(preds, META, deng, cntg);
    gcg_pass2<<<BATCH * 128, 256, 0, stream>>>(x, META, WXg, SXg);
    gcg_epiA<<<BATCH, 256, 0, stream>>>(WXg, SXg, deng, cntg, w1, b1, w2, CF2, S1);
    gcg_epiB<<<BATCH * 8, 256, 0, stream>>>(CF2, S1, b2, out);
}

// Round 10
// 430.339 us; speedup vs baseline: 2.4708x; 1.0346x over previous
//
#include <hip/hip_runtime.h>

#define K_CLS 19
#define C_CH  128
#define NPIX  65536     // 256*256
#define BATCH 8
#define RS2   38        // acc row = 19 float2 pairs = 38 floats (8B-aligned rows)

// ws layout (f32 units) — every word written before read; no zero-init needed:
//   META @ 0        (524288 u32: e-bits | cls)
//   PART @ 524288   (1024 blocks * 152)          = 155648
//   DENP @ 679936   (512 blocks * 38 den|cnt)    = 19456
//   CF2  @ 699392   (19456)
//   S1   @ 718848   (19456)
//   END  @ 738304 f32 = 2.95 MB

// ---------------------------------------------------------------------------
// Pass 1: per-pixel argmax + exp over preds; write packed meta u32
// (e mantissa-truncated, low 5 bits = cls); per-block den/cnt partials.
// ---------------------------------------------------------------------------
__global__ __launch_bounds__(256, 2)
void gcg_pass1(const float* __restrict__ preds, unsigned* __restrict__ meta,
               float* __restrict__ denp)
{
    __shared__ float denl[K_CLS], cntl[K_CLS];
    const int t = threadIdx.x;
    const int b = blockIdx.x >> 6, blk = blockIdx.x & 63;
    if (t < K_CLS) { denl[t] = 0.f; cntl[t] = 0.f; }
    __syncthreads();

    const int n0 = blk * 1024 + 4 * t;
    const float* pb = preds + (size_t)b * K_CLS * NPIX + n0;

    float4 bv = *reinterpret_cast<const float4*>(pb);
    int k0 = 0, k1 = 0, k2 = 0, k3 = 0;
    #pragma unroll
    for (int k = 1; k < K_CLS; ++k) {
        const float4 p = *reinterpret_cast<const float4*>(pb + (size_t)k * NPIX);
        if (p.x > bv.x) { bv.x = p.x; k0 = k; }
        if (p.y > bv.y) { bv.y = p.y; k1 = k; }
        if (p.z > bv.z) { bv.z = p.z; k2 = k; }
        if (p.w > bv.w) { bv.w = p.w; k3 = k; }
    }
    uint4 m;
    m.x = (__float_as_uint(__expf(bv.x)) & 0xFFFFFFE0u) | (unsigned)k0;
    m.y = (__float_as_uint(__expf(bv.y)) & 0xFFFFFFE0u) | (unsigned)k1;
    m.z = (__float_as_uint(__expf(bv.z)) & 0xFFFFFFE0u) | (unsigned)k2;
    m.w = (__float_as_uint(__expf(bv.w)) & 0xFFFFFFE0u) | (unsigned)k3;
    *reinterpret_cast<uint4*>(meta + (size_t)b * NPIX + n0) = m;

    atomicAdd(&denl[k0], __uint_as_float(m.x & 0xFFFFFFE0u)); atomicAdd(&cntl[k0], 1.f);
    atomicAdd(&denl[k1], __uint_as_float(m.y & 0xFFFFFFE0u)); atomicAdd(&cntl[k1], 1.f);
    atomicAdd(&denl[k2], __uint_as_float(m.z & 0xFFFFFFE0u)); atomicAdd(&cntl[k2], 1.f);
    atomicAdd(&denl[k3], __uint_as_float(m.w & 0xFFFFFFE0u)); atomicAdd(&cntl[k3], 1.f);
    __syncthreads();
    if (t < K_CLS) {
        denp[(size_t)blockIdx.x * RS2 + t]         = denl[t];
        denp[(size_t)blockIdx.x * RS2 + K_CLS + t] = cntl[t];
    }
}

// ---------------------------------------------------------------------------
// Pass 2: wave = one channel, lanes = pixels (coalesced 1KB x-loads).
// Per-thread private LDS row of 19 {WX,SX} float2 pairs -> one ds_read_b64 +
// one ds_write_b64 per pixel. No atomics, no hot-loop barriers.
// Flush: per-block partials to unique global slots (no atomics).
// ---------------------------------------------------------------------------
__global__ __launch_bounds__(256, 4)
void gcg_pass2(const float* __restrict__ x, const unsigned* __restrict__ meta,
               float* __restrict__ part)
{
    __shared__ float acc[256 * RS2];         // 38912 B -> 4 blocks/CU
    const int t = threadIdx.x, w = t >> 6, l = t & 63;
    const int b = blockIdx.x >> 7;           // 1024 blocks = 8 b * 32 cgrp * 4 q
    const int r = blockIdx.x & 127;
    const int cgrp = r >> 2, q = r & 3;
    const int c = cgrp * 4 + w;

    float* arow = &acc[t * RS2];
    #pragma unroll
    for (int s = 0; s < RS2; ++s) arow[s] = 0.f;

    const float*    xr = x    + ((size_t)(b * C_CH + c)) * NPIX + q * 16384;
    const unsigned* mr = meta + (size_t)b * NPIX + q * 16384;

    #pragma unroll 4
    for (int i = 0; i < 64; ++i) {
        const int px = i * 256 + 4 * l;
        const float4 x4 = *reinterpret_cast<const float4*>(xr + px);
        const uint4  m4 = *reinterpret_cast<const uint4*>(mr + px);
        {   const int k = (int)(m4.x & 31u);
            const float e = __uint_as_float(m4.x & 0xFFFFFFE0u);
            float2 v = *reinterpret_cast<float2*>(&arow[2 * k]);
            v.x = fmaf(e, x4.x, v.x); v.y += x4.x;
            *reinterpret_cast<float2*>(&arow[2 * k]) = v;
        }
        {   const int k = (int)(m4.y & 31u);
            const float e = __uint_as_float(m4.y & 0xFFFFFFE0u);
            float2 v = *reinterpret_cast<float2*>(&arow[2 * k]);
            v.x = fmaf(e, x4.y, v.x); v.y += x4.y;
            *reinterpret_cast<float2*>(&arow[2 * k]) = v;
        }
        {   const int k = (int)(m4.z & 31u);
            const float e = __uint_as_float(m4.z & 0xFFFFFFE0u);
            float2 v = *reinterpret_cast<float2*>(&arow[2 * k]);
            v.x = fmaf(e, x4.z, v.x); v.y += x4.z;
            *reinterpret_cast<float2*>(&arow[2 * k]) = v;
        }
        {   const int k = (int)(m4.w & 31u);
            const float e = __uint_as_float(m4.w & 0xFFFFFFE0u);
            float2 v = *reinterpret_cast<float2*>(&arow[2 * k]);
            v.x = fmaf(e, x4.w, v.x); v.y += x4.w;
            *reinterpret_cast<float2*>(&arow[2 * k]) = v;
        }
    }
    __syncthreads();

    // flush: 152 jobs = {WX,SX} x 4 waves x 19 classes; each sums 64 lane-rows
    if (t < 2 * 4 * K_CLS) {
        const int arr = t / (4 * K_CLS), rem = t % (4 * K_CLS);
        const int ww = rem / K_CLS, k = rem % K_CLS;
        float s0 = 0.f;
        #pragma unroll 8
        for (int ll = 0; ll < 64; ++ll)
            s0 += acc[(ww * 64 + ll) * RS2 + 2 * k + arr];
        part[(size_t)blockIdx.x * 152 + arr * 76 + ww * K_CLS + k] = s0;
    }
}

// ---------------------------------------------------------------------------
// Epilogue A: 16 blocks = (batch, half). half 0: reduce den+WX, cf2 = cf@w2^T.
// half 1: reduce cnt+SX, S1 = w1@SX^T + b1*cnt. Weights staged stride-129.
// ---------------------------------------------------------------------------
__global__ __launch_bounds__(256, 1)
void gcg_epiA(const float* __restrict__ part, const float* __restrict__ denp,
              const float* __restrict__ w1, const float* __restrict__ b1,
              const float* __restrict__ w2,
              float* __restrict__ cf2g, float* __restrict__ S1g)
{
    __shared__ float wb[C_CH * 129];
    __shared__ float fb[K_CLS * 129];
    __shared__ float redb[K_CLS];
    const int t = threadIdx.x;
    const int b = blockIdx.x >> 1, half = blockIdx.x & 1;

    // stage weight matrix (w2 for half 0, w1 for half 1)
    const float* wsrc = half ? w1 : w2;
    for (int f = t; f < C_CH * C_CH / 4; f += 256) {
        const int d = f >> 5, c4 = (f & 31) << 2;
        const float4 v = *reinterpret_cast<const float4*>(wsrc + d * C_CH + c4);
        float* p = &wb[d * 129 + c4];
        p[0] = v.x; p[1] = v.y; p[2] = v.z; p[3] = v.w;
    }
    // reduce den (half 0) / cnt (half 1) over 64 pass1 blocks
    if (t < K_CLS) {
        float s0 = 0.f;
        const float* dp = denp + (size_t)(b * 64) * RS2 + half * K_CLS + t;
        for (int blk = 0; blk < 64; ++blk) s0 += dp[(size_t)blk * RS2];
        redb[t] = s0;
    }
    __syncthreads();

    // reduce WX (half 0) / SX (half 1) over 4 q-partials; fb[k][c]
    for (int i = t; i < K_CLS * C_CH; i += 256) {
        const int k = i >> 7, c = i & 127;
        const int cgrp = c >> 2, ww = c & 3;
        const float* pp = part + (size_t)(b * 128 + cgrp * 4) * 152 + half * 76 + ww * K_CLS + k;
        float s0 = pp[0] + pp[152] + pp[304] + pp[456];
        if (half == 0) s0 /= fmaxf(redb[k], 1e-30f);
        fb[k * 129 + c] = s0;
    }
    __syncthreads();

    if (half == 0) {
        // cf2[k][d] = sum_c fb[k][c] * w2[d][c]
        for (int i = t; i < K_CLS * C_CH; i += 256) {
            const int k = i >> 7, d = i & 127;
            float a = 0.f;
            #pragma unroll 8
            for (int c = 0; c < C_CH; ++c) a = fmaf(fb[k * 129 + c], wb[d * 129 + c], a);
            cf2g[(size_t)b * K_CLS * C_CH + k * C_CH + d] = a;
        }
    } else {
        // S1[d][k] = sum_c w1[d][c] * SX[k][c] + b1[d]*cnt[k]
        for (int i = t; i < C_CH * K_CLS; i += 256) {
            const int d = i / K_CLS, k = i % K_CLS;
            float a = 0.f;
            #pragma unroll 8
            for (int c = 0; c < C_CH; ++c) a = fmaf(wb[d * 129 + c], fb[k * 129 + c], a);
            S1g[(size_t)b * C_CH * K_CLS + d * K_CLS + k] = a + b1[d] * redb[k];
        }
    }
}

// ---------------------------------------------------------------------------
// Epilogue B: 8 blocks/batch, 16 gc rows each: gc = S1 @ cf2 + T*b2, row softmax.
// ---------------------------------------------------------------------------
__global__ __launch_bounds__(256, 1)
void gcg_epiB(const float* __restrict__ cf2g, const float* __restrict__ S1g,
              const float* __restrict__ b2, float* __restrict__ out)
{
    __shared__ float cf2b[K_CLS * 132];
    __shared__ float S1b[16][20];
    __shared__ float b2b[C_CH];
    __shared__ float gcb[16][C_CH + 1];
    const int t = threadIdx.x;
    const int b = blockIdx.x >> 3, sl = blockIdx.x & 7;
    const int r0 = sl * 16;

    for (int i = t; i < K_CLS * C_CH; i += 256)
        cf2b[(i >> 7) * 132 + (i & 127)] = cf2g[(size_t)b * K_CLS * C_CH + i];
    for (int i = t; i < 16 * K_CLS; i += 256) {      // 304 jobs, strided
        const int rr = i / K_CLS, k = i % K_CLS;
        S1b[rr][k] = S1g[(size_t)b * C_CH * K_CLS + (r0 + rr) * K_CLS + k];
    }
    if (t < C_CH) b2b[t] = b2[t];
    __syncthreads();

    {
        const int rr = t >> 4, d0 = (t & 15) * 8;
        float a0=0,a1=0,a2=0,a3=0,a4=0,a5=0,a6=0,a7=0, T = 0.f;
        #pragma unroll
        for (int k = 0; k < K_CLS; ++k) {
            const float sv = S1b[rr][k];
            T += sv;
            const float* row = &cf2b[k * 132 + d0];
            a0 = fmaf(sv, row[0], a0); a1 = fmaf(sv, row[1], a1);
            a2 = fmaf(sv, row[2], a2); a3 = fmaf(sv, row[3], a3);
            a4 = fmaf(sv, row[4], a4); a5 = fmaf(sv, row[5], a5);
            a6 = fmaf(sv, row[6], a6); a7 = fmaf(sv, row[7], a7);
        }
        const float s = 0.08838834764831845f;   // 128^-0.5
        float* g = &gcb[rr][d0];
        g[0]=(a0+T*b2b[d0+0])*s; g[1]=(a1+T*b2b[d0+1])*s;
        g[2]=(a2+T*b2b[d0+2])*s; g[3]=(a3+T*b2b[d0+3])*s;
        g[4]=(a4+T*b2b[d0+4])*s; g[5]=(a5+T*b2b[d0+5])*s;
        g[6]=(a6+T*b2b[d0+6])*s; g[7]=(a7+T*b2b[d0+7])*s;
    }
    __syncthreads();

    const int wv = t >> 6, lane = t & 63;
    for (int rr = wv; rr < 16; rr += 4) {
        float v0 = gcb[rr][lane], v1 = gcb[rr][lane + 64];
        float m = fmaxf(v0, v1);
        #pragma unroll
        for (int o = 32; o > 0; o >>= 1) m = fmaxf(m, __shfl_xor(m, o));
        const float e0 = __expf(v0 - m), e1 = __expf(v1 - m);
        float ss = e0 + e1;
        #pragma unroll
        for (int o = 32; o > 0; o >>= 1) ss += __shfl_xor(ss, o);
        const float inv = 1.0f / ss;
        float* orow = out + ((size_t)b * C_CH + r0 + rr) * C_CH;
        orow[lane]      = e0 * inv;
        orow[lane + 64] = e1 * inv;
    }
}

extern "C" void kernel_launch(void* const* d_in, const int* in_sizes, int n_in,
                              void* d_out, int out_size, void* d_ws, size_t ws_size,
                              hipStream_t stream) {
    const float* x     = (const float*)d_in[0];
    const float* preds = (const float*)d_in[1];
    const float* w1    = (const float*)d_in[2];
    const float* b1    = (const float*)d_in[3];
    const float* w2    = (const float*)d_in[4];
    const float* b2    = (const float*)d_in[5];
    float* out = (float*)d_out;

    float* ws      = (float*)d_ws;
    unsigned* META = (unsigned*)ws;
    float* PART = ws + 524288;
    float* DENP = ws + 679936;
    float* CF2  = ws + 699392;
    float* S1   = ws + 718848;

    gcg_pass1<<<BATCH * 64, 256, 0, stream>>>(preds, META, DENP);
    gcg_pass2<<<BATCH * 128, 256, 0, stream>>>(x, META, PART);
    gcg_epiA<<<BATCH * 2, 256, 0, stream>>>(PART, DENP, w1, b1, w2, CF2, S1);
    gcg_epiB<<<BATCH * 8, 256, 0, stream>>>(CF2, S1, b2, out);
}